// Round 13
// baseline (303.480 us; speedup 1.0000x reference)
//
#include <hip/hip_runtime.h>
#include <math.h>
#include <stdint.h>

#define M_NODES 8192
#define E_DIM   512
#define NTOPK   6
#define ATTN_SCALE 0.04419417382415922f  // 512^-0.5

typedef __attribute__((ext_vector_type(8))) short short8;
typedef __attribute__((ext_vector_type(4))) float f32x4;

__device__ __forceinline__ float lrelu(float v) { return v > 0.f ? v : 0.01f * v; }

__device__ __forceinline__ unsigned short f2bf(float f) {
  uint32_t u = __float_as_uint(f);
  uint32_t r = (u + 0x7FFFu + ((u >> 16) & 1u)) >> 16;
  return (unsigned short)r;
}
__device__ __forceinline__ float bf2f(unsigned short s) {
  return __uint_as_float(((uint32_t)s) << 16);
}

// async 16B/lane global->LDS (wave-uniform LDS base, lane i lands at base+16i)
__device__ __forceinline__ void async_cp16(const void* gptr, void* lds) {
  auto g1 = reinterpret_cast<const __attribute__((address_space(1))) unsigned int*>(
      reinterpret_cast<uintptr_t>(gptr));
  auto l3 = reinterpret_cast<__attribute__((address_space(3))) unsigned int*>(
      reinterpret_cast<uintptr_t>(lds));
  __builtin_amdgcn_global_load_lds(g1, l3, 16, 0, 0);
}

// tiled bf16 layout: value (m,k), Ktiles=K/32:
//   idx = ((m>>4)*Ktiles + (k>>5))*512 + ((m&15) + 16*((k>>3)&3))*8 + (k&7)

// top-k key scheme (r6/r8-verified): key = ordered16(bf16) << 16 | (8191-col).
// ordered16: sign=0 -> h|0x8000 ; sign=1 -> ~h. Value order preserved, ties
// break to LOWER col (lax.top_k semantics). Keys unique per row.

// BK=64 K-loops (r12-verified): stage TWO 32-k tiles per barrier pair, slot
// (s*2+h)*512 <- source k-tile 2*kt8+h. Halves barrier/drain windows.

// ---------------------------------------------------------------------------
// Cast fp32 x + 6 weight matrices into bf16 frag-tiled layout.
// Also zeroes the 47232-byte accumulator region (replaces hipMemsetAsync).
// ---------------------------------------------------------------------------
__global__ __launch_bounds__(256) void wcast_kernel(
    const float* __restrict__ x, const float* __restrict__ fc1w,
    const float* __restrict__ whw, const float* __restrict__ wtw,
    const float* __restrict__ l1w, const float* __restrict__ l2w,
    const float* __restrict__ a1w,
    unsigned short* __restrict__ xT, unsigned short* __restrict__ fc1T,
    unsigned short* __restrict__ whT, unsigned short* __restrict__ wtT,
    unsigned short* __restrict__ l1T, unsigned short* __restrict__ l2T,
    unsigned short* __restrict__ a1T, float* __restrict__ zbuf)
{
  const int gid = blockIdx.x * 256 + threadIdx.x;  // 0 .. 565247
  if (gid < 11808) zbuf[gid] = 0.f;                // 47232 B accumulators+ctr
  const float* src; unsigned short* dst; int K8, local;
  if (gid < 417792) {
    K8 = 48;
    if (gid < 393216) { src = x; dst = xT; local = gid; }
    else { src = fc1w; dst = fc1T; local = gid - 393216; }
  } else {
    K8 = 64;
    if (gid < 450560)      { src = whw; dst = whT; local = gid - 417792; }
    else if (gid < 483328) { src = wtw; dst = wtT; local = gid - 450560; }
    else if (gid < 516096) { src = l1w; dst = l1T; local = gid - 483328; }
    else if (gid < 548864) { src = l2w; dst = l2T; local = gid - 516096; }
    else                   { src = a1w; dst = a1T; local = gid - 548864; }
  }
  const int m = local / K8;
  const int k8 = local - m * K8;
  const float* p = src + (size_t)m * (K8 * 8) + k8 * 8;
  float4 v0 = ((const float4*)p)[0];
  float4 v1 = ((const float4*)p)[1];
  const int Kt = K8 >> 2;
  const size_t ti = ((size_t)(m >> 4) * Kt + (k8 >> 2)) * 512 + ((m & 15) + 16 * (k8 & 3)) * 8;
  uint4 pk;
  pk.x = (uint32_t)f2bf(v0.x) | ((uint32_t)f2bf(v0.y) << 16);
  pk.y = (uint32_t)f2bf(v0.z) | ((uint32_t)f2bf(v0.w) << 16);
  pk.z = (uint32_t)f2bf(v1.x) | ((uint32_t)f2bf(v1.y) << 16);
  pk.w = (uint32_t)f2bf(v1.z) | ((uint32_t)f2bf(v1.w) << 16);
  *(uint4*)(dst + ti) = pk;
}

// ---------------------------------------------------------------------------
// gemm1: hT = bf16(0.5*lrelu(x @ fc1^T + b)) tiled + fused column sums.
// 128x128 tile, grid (4,64), K=384: 6 BK=64 iterations.
// ---------------------------------------------------------------------------
__global__ __launch_bounds__(256, 4) void gemm1_kernel(
    const unsigned short* __restrict__ xT, const unsigned short* __restrict__ fc1T,
    const float* __restrict__ b1, unsigned short* __restrict__ hT,
    float* __restrict__ colsum)
{
  __shared__ unsigned short As[16 * 512];
  __shared__ unsigned short Bs[16 * 512];
  const int tid = threadIdx.x, lane = tid & 63, w = tid >> 6;
  const int wr = w >> 1, wc = w & 1;
  const int m0 = blockIdx.y * 128;
  const int n0 = blockIdx.x * 128;

  f32x4 acc[4][4];
#pragma unroll
  for (int i = 0; i < 4; i++)
#pragma unroll
    for (int j = 0; j < 4; j++) acc[i][j] = (f32x4){0.f, 0.f, 0.f, 0.f};

  auto stage = [&](int kt8) {
    const int s0 = w, s1 = w + 4;
#pragma unroll
    for (int h = 0; h < 2; h++) {
      const int kt = 2 * kt8 + h;
      async_cp16(xT + ((size_t)((m0 >> 4) + s0) * 12 + kt) * 512 + lane * 8, &As[(s0 * 2 + h) * 512]);
      async_cp16(xT + ((size_t)((m0 >> 4) + s1) * 12 + kt) * 512 + lane * 8, &As[(s1 * 2 + h) * 512]);
      async_cp16(fc1T + ((size_t)((n0 >> 4) + s0) * 12 + kt) * 512 + lane * 8, &Bs[(s0 * 2 + h) * 512]);
      async_cp16(fc1T + ((size_t)((n0 >> 4) + s1) * 12 + kt) * 512 + lane * 8, &Bs[(s1 * 2 + h) * 512]);
    }
  };
  stage(0);

  for (int kt8 = 0; kt8 < 6; kt8++) {
    __syncthreads();
#pragma unroll
    for (int h = 0; h < 2; h++) {
      short8 a[4], b[4];
#pragma unroll
      for (int i = 0; i < 4; i++) a[i] = *(const short8*)&As[((wr * 4 + i) * 2 + h) * 512 + lane * 8];
#pragma unroll
      for (int j = 0; j < 4; j++) b[j] = *(const short8*)&Bs[((wc * 4 + j) * 2 + h) * 512 + lane * 8];
#pragma unroll
      for (int i = 0; i < 4; i++)
#pragma unroll
        for (int j = 0; j < 4; j++)
          acc[i][j] = __builtin_amdgcn_mfma_f32_16x16x32_bf16(a[i], b[j], acc[i][j], 0, 0, 0);
    }
    __syncthreads();
    if (kt8 < 5) stage(kt8 + 1);
  }

  const int q = lane >> 4, lcol = lane & 15;
  float colp[4] = {};
#pragma unroll
  for (int i = 0; i < 4; i++)
#pragma unroll
    for (int j = 0; j < 4; j++) {
      const int c = n0 + wc * 64 + j * 16 + lcol;
      const float bias = b1[c];
#pragma unroll
      for (int d = 0; d < 4; d++) {
        const int r = m0 + wr * 64 + i * 16 + q * 4 + d;
        const float v = 0.5f * lrelu(acc[i][j][d] + bias);
        hT[((size_t)(r >> 4) * 16 + (c >> 5)) * 512 +
           ((r & 15) + 16 * ((c >> 3) & 3)) * 8 + (c & 7)] = f2bf(v);
        colp[j] += v;
      }
    }
#pragma unroll
  for (int j = 0; j < 4; j++) {
    colp[j] += __shfl_xor(colp[j], 16);
    colp[j] += __shfl_xor(colp[j], 32);
  }
  if (lane < 16) {
#pragma unroll
    for (int j = 0; j < 4; j++)
      atomicAdd(&colsum[n0 + wc * 64 + j * 16 + lcol], colp[j]);
  }
}

// ---------------------------------------------------------------------------
// meanproj: biasHT[c1024] = {wh_b|wt_b}[c] + (colsum/M) . {wh_w|wt_w}[c,:]
// (colsum holds 0.5-scaled sums, so this is Wh·(0.5·mean).) One wave per c.
// ---------------------------------------------------------------------------
__global__ __launch_bounds__(256) void meanproj_kernel(
    const float* __restrict__ colsum, const float* __restrict__ whw,
    const float* __restrict__ wtw, const float* __restrict__ whb,
    const float* __restrict__ wtb, float* __restrict__ biasHT)
{
  const int lane = threadIdx.x & 63;
  const int c1024 = blockIdx.x * 4 + (threadIdx.x >> 6);
  const bool isH = c1024 < 512;
  const int c = isH ? c1024 : c1024 - 512;
  const float* W = (isH ? whw : wtw) + (size_t)c * 512 + lane * 8;
  const float* cs = colsum + lane * 8;
  float s = 0.f;
#pragma unroll
  for (int e = 0; e < 8; e++) s = fmaf(cs[e], W[e], s);
#pragma unroll
  for (int off = 32; off; off >>= 1) s += __shfl_xor(s, off);
  if (lane == 0)
    biasHT[c1024] = (isH ? whb : wtb)[c] + s * (1.f / (float)M_NODES);
}

// ---------------------------------------------------------------------------
// dual_gemm: [e_h | e_t] = hT @ [Wh|Wt]^T + biasHT  (stacked 1024-col weight,
// whT/wtT contiguous). 128x128 tile, grid (8,64), K=512: 8 BK=64 iterations.
// Outputs: tiled (for sgemm) + ROW-MAJOR (for combine — r9 lesson).
// ---------------------------------------------------------------------------
__global__ __launch_bounds__(256, 4) void dual_gemm(
    const unsigned short* __restrict__ hT, const unsigned short* __restrict__ wstackT,
    const float* __restrict__ biasHT,
    unsigned short* __restrict__ ehT, unsigned short* __restrict__ etT,
    unsigned short* __restrict__ ehRow, unsigned short* __restrict__ etRow)
{
  __shared__ unsigned short As[16 * 512];
  __shared__ unsigned short Bs[16 * 512];
  const int tid = threadIdx.x, lane = tid & 63, w = tid >> 6;
  const int wr = w >> 1, wc = w & 1;
  const int m0 = blockIdx.y * 128;
  const int n0 = blockIdx.x * 128;  // [0,1024)

  f32x4 acc[4][4];
#pragma unroll
  for (int i = 0; i < 4; i++)
#pragma unroll
    for (int j = 0; j < 4; j++) acc[i][j] = (f32x4){0.f, 0.f, 0.f, 0.f};

  auto stage = [&](int kt8) {
    const int s0 = w, s1 = w + 4;
#pragma unroll
    for (int h = 0; h < 2; h++) {
      const int kt = 2 * kt8 + h;
      async_cp16(hT + ((size_t)((m0 >> 4) + s0) * 16 + kt) * 512 + lane * 8, &As[(s0 * 2 + h) * 512]);
      async_cp16(hT + ((size_t)((m0 >> 4) + s1) * 16 + kt) * 512 + lane * 8, &As[(s1 * 2 + h) * 512]);
      async_cp16(wstackT + ((size_t)((n0 >> 4) + s0) * 16 + kt) * 512 + lane * 8, &Bs[(s0 * 2 + h) * 512]);
      async_cp16(wstackT + ((size_t)((n0 >> 4) + s1) * 16 + kt) * 512 + lane * 8, &Bs[(s1 * 2 + h) * 512]);
    }
  };
  stage(0);

  for (int kt8 = 0; kt8 < 8; kt8++) {
    __syncthreads();
#pragma unroll
    for (int h = 0; h < 2; h++) {
      short8 a[4], b[4];
#pragma unroll
      for (int i = 0; i < 4; i++) a[i] = *(const short8*)&As[((wr * 4 + i) * 2 + h) * 512 + lane * 8];
#pragma unroll
      for (int j = 0; j < 4; j++) b[j] = *(const short8*)&Bs[((wc * 4 + j) * 2 + h) * 512 + lane * 8];
#pragma unroll
      for (int i = 0; i < 4; i++)
#pragma unroll
        for (int j = 0; j < 4; j++)
          acc[i][j] = __builtin_amdgcn_mfma_f32_16x16x32_bf16(a[i], b[j], acc[i][j], 0, 0, 0);
    }
    __syncthreads();
    if (kt8 < 7) stage(kt8 + 1);
  }

  const int q = lane >> 4, lcol = lane & 15;
  const bool isH = (n0 < 512);                 // block-uniform
  const int cb = isH ? n0 : (n0 - 512);
  unsigned short* T = isH ? ehT : etT;
  unsigned short* R = isH ? ehRow : etRow;

#pragma unroll
  for (int i = 0; i < 4; i++)
#pragma unroll
    for (int j = 0; j < 4; j++) {
      const int cl = wc * 64 + j * 16 + lcol;
      const float bias = biasHT[n0 + cl];
      const int c = cb + cl;
#pragma unroll
      for (int d = 0; d < 4; d++) {
        const int r = m0 + wr * 64 + i * 16 + q * 4 + d;
        const unsigned short us = f2bf(acc[i][j][d] + bias);
        T[((size_t)(r >> 4) * 16 + (c >> 5)) * 512 +
          ((r & 15) + 16 * ((c >> 3) & 3)) * 8 + (c & 7)] = us;
        R[(size_t)r * E_DIM + c] = us;
      }
    }
}

// ---------------------------------------------------------------------------
// MFMA GEMM, tile 128(M) x 64(N), 4 waves each 32x64, K-step 32.
// MODE 2: e = lrelu(A1@W1^T+b1)+lrelu(A2@W2^T+b2); T1 = bf16(e) tiled;
//         Cbf = bf16(e) row-major
// MODE 3: g[r] += sum_c lrelu(A@W1^T+b1)[r,c] * b2[c]  (fused gate readout)
// ---------------------------------------------------------------------------
template <int MODE>
__global__ __launch_bounds__(256) void mfma_gemm(
    const unsigned short* __restrict__ At1, const unsigned short* __restrict__ At2,
    const unsigned short* __restrict__ Wt1, const unsigned short* __restrict__ Wt2,
    const float* __restrict__ b1, const float* __restrict__ b2,
    float* __restrict__ Cf, unsigned short* __restrict__ T1,
    unsigned short* __restrict__ Cbf, int N, int K)
{
  constexpr bool DUALW = (MODE == 2);
  __shared__ unsigned short As[2][8 * 512];
  __shared__ unsigned short Bs[2][4 * 512];
  const int Kt = K >> 5;
  const int tid = threadIdx.x, lane = tid & 63, w = tid >> 6;
  const int m0 = blockIdx.y * 128, n0 = blockIdx.x * 64;

  f32x4 acc0[2][4], acc1[2][4];
#pragma unroll
  for (int p = 0; p < 2; p++)
#pragma unroll
    for (int j = 0; j < 4; j++) {
      acc0[p][j] = (f32x4){0.f, 0.f, 0.f, 0.f};
      acc1[p][j] = (f32x4){0.f, 0.f, 0.f, 0.f};
    }

  for (int kt = 0; kt < Kt; kt++) {
    const unsigned short* a1p = At1 + ((size_t)((m0 >> 4) + 2 * w) * Kt + kt) * 512 + lane * 8;
    async_cp16(a1p, &As[0][(2 * w) * 512]);
    async_cp16(a1p + (size_t)Kt * 512, &As[0][(2 * w + 1) * 512]);
    if (MODE == 2) {
      const unsigned short* a2p = At2 + ((size_t)((m0 >> 4) + 2 * w) * Kt + kt) * 512 + lane * 8;
      async_cp16(a2p, &As[1][(2 * w) * 512]);
      async_cp16(a2p + (size_t)Kt * 512, &As[1][(2 * w + 1) * 512]);
    }
    const unsigned short* bp1 = Wt1 + ((size_t)((n0 >> 4) + w) * Kt + kt) * 512 + lane * 8;
    async_cp16(bp1, &Bs[0][w * 512]);
    if (DUALW) {
      const unsigned short* bp2 = Wt2 + ((size_t)((n0 >> 4) + w) * Kt + kt) * 512 + lane * 8;
      async_cp16(bp2, &Bs[1][w * 512]);
    }
    __syncthreads();
    short8 a[2], a2[2], bb[4], bb2[4];
#pragma unroll
    for (int p = 0; p < 2; p++) a[p] = *(const short8*)&As[0][(2 * w + p) * 512 + lane * 8];
    if (MODE == 2) {
#pragma unroll
      for (int p = 0; p < 2; p++) a2[p] = *(const short8*)&As[1][(2 * w + p) * 512 + lane * 8];
    }
#pragma unroll
    for (int j = 0; j < 4; j++) bb[j] = *(const short8*)&Bs[0][j * 512 + lane * 8];
    if (DUALW) {
#pragma unroll
      for (int j = 0; j < 4; j++) bb2[j] = *(const short8*)&Bs[1][j * 512 + lane * 8];
    }
#pragma unroll
    for (int p = 0; p < 2; p++)
#pragma unroll
      for (int j = 0; j < 4; j++) {
        acc0[p][j] = __builtin_amdgcn_mfma_f32_16x16x32_bf16(a[p], bb[j], acc0[p][j], 0, 0, 0);
        if (MODE == 2)
          acc1[p][j] = __builtin_amdgcn_mfma_f32_16x16x32_bf16(a2[p], bb2[j], acc1[p][j], 0, 0, 0);
      }
    __syncthreads();
  }

  const int lrow = (lane >> 4) * 4, lcol = lane & 15;

  if (MODE == 3) {
    float part[2][4] = {};
#pragma unroll
    for (int p = 0; p < 2; p++)
#pragma unroll
      for (int j = 0; j < 4; j++) {
        const int c = n0 + j * 16 + lcol;
        const float bias1 = b1[c];
        const float w2 = b2[c];
#pragma unroll
        for (int d = 0; d < 4; d++)
          part[p][d] = fmaf(lrelu(acc0[p][j][d] + bias1), w2, part[p][d]);
      }
#pragma unroll
    for (int p = 0; p < 2; p++)
#pragma unroll
      for (int d = 0; d < 4; d++) {
#pragma unroll
        for (int off = 1; off < 16; off <<= 1)
          part[p][d] += __shfl_xor(part[p][d], off);
      }
    if (lcol == 0) {
#pragma unroll
      for (int p = 0; p < 2; p++)
#pragma unroll
        for (int d = 0; d < 4; d++)
          atomicAdd(&Cf[m0 + w * 32 + p * 16 + lrow + d], part[p][d]);
    }
    return;
  }

  const int NT = N >> 5;
#pragma unroll
  for (int p = 0; p < 2; p++)
#pragma unroll
    for (int j = 0; j < 4; j++) {
      const int c = n0 + j * 16 + lcol;
      const float bias1 = b1[c];
      const float bias2 = b2[c];
#pragma unroll
      for (int d = 0; d < 4; d++) {
        const int r = m0 + w * 32 + p * 16 + lrow + d;
        const float e = lrelu(acc0[p][j][d] + bias1) + lrelu(acc1[p][j][d] + bias2);
        T1[((size_t)(r >> 4) * NT + (c >> 5)) * 512 +
           ((r & 15) + 16 * ((c >> 3) & 3)) * 8 + (c & 7)] = f2bf(e);
        Cbf[(size_t)r * N + c] = f2bf(e);
      }
    }
}

// ---------------------------------------------------------------------------
// Score GEMM with fused per-128-col-block top-6. K-loop: 8 BK=64 iterations
// (staging 32KB aliased inside the 33,280B score tile; barrier count halved).
// Epilogue (r9-verified): permuted u32 dump + packed sign-transform +
// value-only prefilter + insertion sort + pair-merge + coalesced cand write.
// ---------------------------------------------------------------------------
__global__ __launch_bounds__(256, 4) void sgemm_kernel(
    const unsigned short* __restrict__ ehT, const unsigned short* __restrict__ etT,
    uint32_t* __restrict__ cand)
{
  __shared__ unsigned short SH[128 * 130];          // 33,280 B
  unsigned short* As = SH;                          // [0, 8192) u16  (16 KB)
  unsigned short* Bs = SH + 8192;                   // [8192, 16384) u16
  const int tid = threadIdx.x, lane = tid & 63, w = tid >> 6;
  const int wr = w >> 1, wc = w & 1;
  const int m0 = blockIdx.y * 128;
  const int n0 = blockIdx.x * 128;

  f32x4 acc[4][4];
#pragma unroll
  for (int i = 0; i < 4; i++)
#pragma unroll
    for (int j = 0; j < 4; j++) acc[i][j] = (f32x4){0.f, 0.f, 0.f, 0.f};

  auto stage = [&](int kt8) {
    const int s0 = w, s1 = w + 4;
#pragma unroll
    for (int h = 0; h < 2; h++) {
      const int kt = 2 * kt8 + h;
      async_cp16(ehT + ((size_t)((m0 >> 4) + s0) * 16 + kt) * 512 + lane * 8, &As[(s0 * 2 + h) * 512]);
      async_cp16(ehT + ((size_t)((m0 >> 4) + s1) * 16 + kt) * 512 + lane * 8, &As[(s1 * 2 + h) * 512]);
      async_cp16(etT + ((size_t)((n0 >> 4) + s0) * 16 + kt) * 512 + lane * 8, &Bs[(s0 * 2 + h) * 512]);
      async_cp16(etT + ((size_t)((n0 >> 4) + s1) * 16 + kt) * 512 + lane * 8, &Bs[(s1 * 2 + h) * 512]);
    }
  };
  stage(0);

  for (int kt8 = 0; kt8 < 8; kt8++) {
    __syncthreads();
#pragma unroll
    for (int h = 0; h < 2; h++) {
      short8 a[4], b[4];
#pragma unroll
      for (int i = 0; i < 4; i++) a[i] = *(const short8*)&As[((wr * 4 + i) * 2 + h) * 512 + lane * 8];
#pragma unroll
      for (int j = 0; j < 4; j++) b[j] = *(const short8*)&Bs[((wc * 4 + j) * 2 + h) * 512 + lane * 8];
#pragma unroll
      for (int i = 0; i < 4; i++)
#pragma unroll
        for (int j = 0; j < 4; j++)
          acc[i][j] = __builtin_amdgcn_mfma_f32_16x16x32_bf16(a[i], b[j], acc[i][j], 0, 0, 0);
    }
    __syncthreads();
    if (kt8 < 7) stage(kt8 + 1);
  }
  // Loop ended with a barrier; all staging reads retired -> SH reusable.

  const int q = lane >> 4, lcol = lane & 15;

  // dump bf16-rounded scores, permuted: SH[rowb][c'], c' = wc*64 + lcol*4 + j
#pragma unroll
  for (int i = 0; i < 4; i++)
#pragma unroll
    for (int d = 0; d < 4; d++) {
      const int rowb = wr * 64 + i * 16 + q * 4 + d;
      const uint32_t p01 = (uint32_t)f2bf(acc[i][0][d]) | ((uint32_t)f2bf(acc[i][1][d]) << 16);
      const uint32_t p23 = (uint32_t)f2bf(acc[i][2][d]) | ((uint32_t)f2bf(acc[i][3][d]) << 16);
      uint32_t* wp = (uint32_t*)(SH + rowb * 130 + wc * 64 + lcol * 4);
      wp[0] = p01;
      wp[1] = p23;
    }
  __syncthreads();

  // per-half-row scan: thread t -> row t>>1, half t&1 (c' in [half*64, +64))
  const int r = tid >> 1, half = tid & 1;
  const uint32_t* rowp = (const uint32_t*)SH + r * 65 + half * 32;
  uint32_t t0 = 0, t1 = 0, t2 = 0, t3 = 0, t4 = 0, t5 = 0;
#pragma unroll 8
  for (int cc = 0; cc < 32; cc++) {
    const uint32_t v = rowp[cc];
    const uint32_t sgn = v & 0x80008000u;
    const uint32_t ov = v ^ (0x80008000u | ((sgn >> 15) * 0x7FFFu));  // both ordered16
#pragma unroll
    for (int e = 0; e < 2; e++) {
      const uint32_t o16 = e ? (ov >> 16) : (ov & 0xFFFFu);
      if (o16 >= (t5 >> 16)) {            // value-only prefilter (exact reject)
        const int cperm = half * 64 + cc * 2 + e;
        const int col = n0 + (cperm >> 6) * 64 + (cperm & 3) * 16 + ((cperm >> 2) & 15);
        const uint32_t k = (o16 << 16) | (uint32_t)(8191 - col);
        if (k > t5) {
          t5 = k;
          uint32_t tmp;
          if (t5 > t4) { tmp = t4; t4 = t5; t5 = tmp; }
          if (t4 > t3) { tmp = t3; t3 = t4; t4 = tmp; }
          if (t3 > t2) { tmp = t2; t2 = t3; t3 = tmp; }
          if (t2 > t1) { tmp = t1; t1 = t2; t2 = tmp; }
          if (t1 > t0) { tmp = t0; t0 = t1; t1 = tmp; }
        }
      }
    }
  }

  // pair-merge (halves of the same row live in adjacent lanes)
  uint32_t b0 = (uint32_t)__shfl_xor((int)t0, 1);
  uint32_t b1 = (uint32_t)__shfl_xor((int)t1, 1);
  uint32_t b2 = (uint32_t)__shfl_xor((int)t2, 1);
  uint32_t b3 = (uint32_t)__shfl_xor((int)t3, 1);
  uint32_t b4 = (uint32_t)__shfl_xor((int)t4, 1);
  uint32_t b5 = (uint32_t)__shfl_xor((int)t5, 1);
  uint32_t wk[6];
#pragma unroll
  for (int t = 0; t < 6; t++) {
    if (t0 > b0) {
      wk[t] = t0;
      t0 = t1; t1 = t2; t2 = t3; t3 = t4; t4 = t5; t5 = 0u;
    } else {
      wk[t] = b0;
      b0 = b1; b1 = b2; b2 = b3; b3 = b4; b4 = b5; b5 = 0u;
    }
  }

  if (half == 0) {
    uint32_t* cp = cand + ((size_t)blockIdx.x * M_NODES + m0 + r) * 6;
    uint2 p01; p01.x = wk[0]; p01.y = wk[1];
    uint2 p23; p23.x = wk[2]; p23.y = wk[3];
    uint2 p45; p45.x = wk[4]; p45.y = wk[5];
    ((uint2*)cp)[0] = p01;
    ((uint2*)cp)[1] = p23;
    ((uint2*)cp)[2] = p45;
  }
}

// ---------------------------------------------------------------------------
// combine: exact global top-6 per row via 64-lane tournament merge of the
// 64 per-block sorted top-6 lists (lane l holds block l's list; head
// advanced by register shift). Row-major e_h/e_t reads (coalesced 1KB/row).
// Then the original combine math (softmax, gate, ka-softmax, s1/s2).
// ---------------------------------------------------------------------------
__global__ __launch_bounds__(256) void combine_kernel(
    const uint32_t* __restrict__ cand,
    const unsigned short* __restrict__ ehRow, const unsigned short* __restrict__ etRow,
    unsigned short* __restrict__ s1T, unsigned short* __restrict__ s2T)
{
  const int tid = threadIdx.x;
  const int lane = tid & 63;
  const int w = tid >> 6;
  const int row = blockIdx.x * 4 + w;
  const int m = row;

  const uint32_t* cp = cand + ((size_t)lane * M_NODES + row) * 6;
  const uint2 v01 = ((const uint2*)cp)[0];
  const uint2 v23 = ((const uint2*)cp)[1];
  const uint2 v45 = ((const uint2*)cp)[2];
  uint32_t a0 = v01.x, a1 = v01.y, a2 = v23.x, a3 = v23.y, a4 = v45.x, a5 = v45.y;

  float wv[NTOPK]; int id[NTOPK];
#pragma unroll
  for (int t = 0; t < NTOPK; t++) {
    uint32_t mm = a0;
#pragma unroll
    for (int off = 1; off < 64; off <<= 1) {
      const uint32_t o = (uint32_t)__shfl_xor((int)mm, off);
      mm = mm > o ? mm : o;
    }
    if (a0 == mm) {                    // unique keys -> exactly one winner
      a0 = a1; a1 = a2; a2 = a3; a3 = a4; a4 = a5; a5 = 0u;
    }
    // decode key -> (bf16 value as f32, col)
    const uint32_t h = mm >> 16;
    const uint32_t u = (h & 0x8000u) ? ((h & 0x7FFFu) << 16)
                                     : ((~h & 0xFFFFu) << 16);
    wv[t] = __uint_as_float(u) * ATTN_SCALE;
    id[t] = 8191 - (int)(mm & 0x1FFFu);
  }

  float mx = wv[0];
#pragma unroll
  for (int k = 1; k < NTOPK; k++) mx = fmaxf(mx, wv[k]);
  float p[NTOPK]; float s = 0.f;
#pragma unroll
  for (int k = 0; k < NTOPK; k++) { p[k] = expf(wv[k] - mx); s += p[k]; }
  const float inv = 1.f / s;
#pragma unroll
  for (int k = 0; k < NTOPK; k++) p[k] *= inv;

  short8 eh8 = *(const short8*)(ehRow + (size_t)m * E_DIM + lane * 8);
  float ehv[8];
#pragma unroll
  for (int e = 0; e < 8; e++) ehv[e] = bf2f((unsigned short)eh8[e]);

  float nv[NTOPK][8];
#pragma unroll
  for (int k = 0; k < NTOPK; k++) {
    short8 nb = *(const short8*)(etRow + (size_t)id[k] * E_DIM + lane * 8);
#pragma unroll
    for (int e = 0; e < 8; e++) nv[k][e] = bf2f((unsigned short)nb[e]);
  }

  float ka[NTOPK];
#pragma unroll
  for (int k = 0; k < NTOPK; k++) {
    float snb = 0.f, sg = 0.f;
    const float aa = 2.f - p[k], bb = p[k];
#pragma unroll
    for (int e = 0; e < 8; e++) {
      snb += nv[k][e];
      sg += tanhf(fmaf(aa, ehv[e], bb * nv[k][e]));
    }
#pragma unroll
    for (int off = 32; off; off >>= 1) {
      snb += __shfl_xor(snb, off);
      sg += __shfl_xor(sg, off);
    }
    ka[k] = snb * sg;
  }
  float km = ka[0];
#pragma unroll
  for (int k = 1; k < NTOPK; k++) km = fmaxf(km, ka[k]);
  float kp[NTOPK]; float ks = 0.f;
#pragma unroll
  for (int k = 0; k < NTOPK; k++) { kp[k] = expf(ka[k] - km); ks += kp[k]; }
  const float kinv = 1.f / ks;

  const size_t tbase = ((size_t)(m >> 4) * 16 + (lane >> 2)) * 512 +
                       ((m & 15) + 16 * (lane & 3)) * 8;
  unsigned short o1[8], o2[8];
#pragma unroll
  for (int e = 0; e < 8; e++) {
    float o = 0.f;
#pragma unroll
    for (int k = 0; k < NTOPK; k++) o = fmaf(kp[k], nv[k][e], o);
    o *= kinv;
    o1[e] = f2bf(ehv[e] + o);
    o2[e] = f2bf(ehv[e] * o);
  }
  *(short8*)(s1T + tbase) = *(short8*)o1;
  *(short8*)(s2T + tbase) = *(short8*)o2;
}

// ---------------------------------------------------------------------------
// pooled + LN fused (last-block-done), 256 blocks x 32 rows (was 64 x 128:
// only 25% of CUs busy -> latency-exposed; same verified atomic pattern,
// counter target 255). Unshifted exp(g) weights (|g| small, fp32-safe).
// Cross-block visibility: __threadfence (release) before the ctr atomic;
// the last block re-reads pooled/wsum via device-scope atomic-add-zero
// (immune to per-CU L1 staleness across XCDs, G16).
// ---------------------------------------------------------------------------
__global__ __launch_bounds__(256) void pooled_ln_kernel(
    const unsigned short* __restrict__ emb, const float* __restrict__ g,
    float* __restrict__ pooled, float* __restrict__ wsum, int* __restrict__ ctr,
    const float* __restrict__ lng, const float* __restrict__ lnb,
    float* __restrict__ out)
{
  const int t = threadIdx.x;
  const int r0 = blockIdx.x * 32;
  float a0 = 0.f, a1 = 0.f, lsum = 0.f;
  for (int r = 0; r < 32; r++) {
    const int m = r0 + r;
    const float wv = expf(g[m]);
    lsum += wv;
    a0 = fmaf(wv, bf2f(emb[(size_t)m * E_DIM + t]), a0);
    a1 = fmaf(wv, bf2f(emb[(size_t)m * E_DIM + 256 + t]), a1);
  }
  atomicAdd(&pooled[t], a0);
  atomicAdd(&pooled[t + 256], a1);
  if (t == 0) atomicAdd(wsum, lsum);

  __threadfence();                         // release our atomics
  __shared__ int lastBlk;
  if (t == 0) lastBlk = (atomicAdd(ctr, 1) == 255) ? 1 : 0;
  __syncthreads();
  if (!lastBlk) return;
  __threadfence();                         // acquire others' atomics

  // LN over 512 elems with 256 threads (elems t and t+256 per thread).
  const float ws = atomicAdd(wsum, 0.f);
  const float v0 = atomicAdd(&pooled[t], 0.f) / ws;
  const float v1 = atomicAdd(&pooled[t + 256], 0.f) / ws;
  __shared__ float red[4];
  __shared__ float red2[4];
  float s = v0 + v1;
#pragma unroll
  for (int off = 32; off; off >>= 1) s += __shfl_xor(s, off);
  if ((t & 63) == 0) red[t >> 6] = s;
  __syncthreads();
  const float mu = (red[0] + red[1] + red[2] + red[3]) / (float)E_DIM;
  const float d0 = v0 - mu, d1 = v1 - mu;
  float q = d0 * d0 + d1 * d1;
#pragma unroll
  for (int off = 32; off; off >>= 1) q += __shfl_xor(q, off);
  if ((t & 63) == 0) red2[t >> 6] = q;
  __syncthreads();
  const float var = (red2[0] + red2[1] + red2[2] + red2[3]) / (float)E_DIM;
  const float inv = rsqrtf(var + 1e-5f);
  out[t]       = d0 * inv * lng[t] + lnb[t];
  out[t + 256] = d1 * inv * lng[t + 256] + lnb[t + 256];
}

// ---------------------------------------------------------------------------
extern "C" void kernel_launch(void* const* d_in, const int* in_sizes, int n_in,
                              void* d_out, int out_size, void* d_ws, size_t ws_size,
                              hipStream_t stream)
{
  const float* x     = (const float*)d_in[0];
  const float* fc1_w = (const float*)d_in[1];
  const float* fc1_b = (const float*)d_in[2];
  const float* wh_w  = (const float*)d_in[3];
  const float* wh_b  = (const float*)d_in[4];
  const float* wt_w  = (const float*)d_in[5];
  const float* wt_b  = (const float*)d_in[6];
  const float* l1_w  = (const float*)d_in[7];
  const float* l1_b  = (const float*)d_in[8];
  const float* l2_w  = (const float*)d_in[9];
  const float* l2_b  = (const float*)d_in[10];
  const float* a1_w  = (const float*)d_in[11];
  const float* a1_b  = (const float*)d_in[12];
  const float* a2_w  = (const float*)d_in[13];
  const float* a2_b  = (const float*)d_in[14];
  const float* ln_g  = (const float*)d_in[15];
  const float* ln_b  = (const float*)d_in[16];
  (void)a2_b;  // exactly cancels in softmax (shift invariance)

  char* ws = (char*)d_ws;
  const size_t MiB = 1 << 20;
  // weight tiles [0, 3M) — live whole run. NOTE: whT/wtT and l1T/l2T are each
  // contiguous pairs -> valid stacked 1024-row tiled tensors.
  unsigned short* fc1T = (unsigned short*)(ws + 0);
  unsigned short* whT  = (unsigned short*)(ws + 393216);
  unsigned short* wtT  = (unsigned short*)(ws + 917504);
  unsigned short* l1T  = (unsigned short*)(ws + 1441792);
  unsigned short* l2T  = (unsigned short*)(ws + 1966080);
  unsigned short* a1T  = (unsigned short*)(ws + 2490368);
  // activations:
  unsigned short* xT     = (unsigned short*)(ws + 3 * MiB);    // [3,9) wcast->gemm1
  unsigned short* hT     = (unsigned short*)(ws + 25 * MiB);   // [25,33) gemm1->dual_gemm
  unsigned short* ehT    = (unsigned short*)(ws + 33 * MiB);   // [33,41) dual_gemm->sgemm
  unsigned short* etT    = (unsigned short*)(ws + 41 * MiB);   // [41,49) dual_gemm->sgemm
  unsigned short* ehRow  = (unsigned short*)(ws + 49 * MiB);   // [49,57) dual_gemm->combine
  unsigned short* etRow  = (unsigned short*)(ws + 57 * MiB);   // [57,65) dual_gemm->combine
  unsigned short* s1T    = (unsigned short*)(ws + 3 * MiB);    // [3,11) combine->gemm3
  unsigned short* s2T    = (unsigned short*)(ws + 11 * MiB);   // [11,19) combine->gemm3
  unsigned short* embT   = (unsigned short*)(ws + 19 * MiB);   // [19,27) gemm3->gemm4
  unsigned short* embRow = (unsigned short*)(ws + 27 * MiB);   // [27,35) gemm3->pooled
  uint32_t*       cand   = (uint32_t*)(ws + 96 * MiB);         // [96,109) sgemm->combine (12.6MB)
  char*           smal   = ws + 69 * MiB;
  float* colsum = (float*)(smal);            // [0, 2048)
  float* biasHT = (float*)(smal + 2048);     // [2048, 6144)
  float* g      = (float*)(smal + 8192);     // [8192, 40960)
  float* stats  = (float*)(smal + 40960);    // wsum
  float* pooled = (float*)(smal + 45056);    // [45056, 47104)
  int*   ctr    = (int*)(smal + 47104);      // pooled_ln completion counter

  // 0. cast x + all weights to bf16 tiled (+ zero 47232B accumulator region)
  wcast_kernel<<<2208, 256, 0, stream>>>(x, fc1_w, wh_w, wt_w, l1_w, l2_w, a1_w,
                                         xT, fc1T, whT, wtT, l1T, l2T, a1T,
                                         (float*)smal);
  // 1. hT = bf16(0.5*lrelu(x@fc1^T+b)) tiled + fused column sums (BK=64)
  gemm1_kernel<<<dim3(4, 64), 256, 0, stream>>>(xT, fc1T, fc1_b, hT, colsum);
  // 2. rank-1 mean projection folded into e_h/e_t biases
  meanproj_kernel<<<256, 256, 0, stream>>>(colsum, wh_w, wt_w, wh_b, wt_b, biasHT);
  // 3. [e_h|e_t] = hT @ [Wh|Wt]^T + biasHT -> tiled + row-major (BK=64)
  dual_gemm<<<dim3(8, 64), 256, 0, stream>>>(hT, whT, biasHT, ehT, etT, ehRow, etRow);
  // 4. score GEMM with fused LDS top-6 (BK=64 K-loop, packed-filter scan)
  sgemm_kernel<<<dim3(64, 64), 256, 0, stream>>>(ehT, etT, cand);
  // 5. exact global top-6 merge + combine (row-major e_h/e_t) -> s1T, s2T
  combine_kernel<<<M_NODES / 4, 256, 0, stream>>>(cand, ehRow, etRow, s1T, s2T);
  // 6. emb = lrelu(s1@l1^T+b1)+lrelu(s2@l2^T+b2) -> bf16 tiled + bf16 row
  mfma_gemm<2><<<dim3(8, 64), 256, 0, stream>>>(
      s1T, s2T, l1T, l2T, l1_b, l2_b, nullptr, embT, embRow, 512, 512);
  // 7. fused: g[m] = sum_c lrelu(emb@a1^T+b)[m,c] * a2w[c]
  mfma_gemm<3><<<dim3(4, 64), 256, 0, stream>>>(
      embT, nullptr, a1T, nullptr, a1_b, a2_w, g, nullptr, nullptr, 256, 512);
  // 8. pooled (fused softmax weights) + layernorm (last-block-done, 256 blk)
  pooled_ln_kernel<<<256, 256, 0, stream>>>(embRow, g, pooled, stats, ctr,
                                            ln_g, ln_b, (float*)d_out);
}

// Round 14
// 289.165 us; speedup vs baseline: 1.0495x; 1.0495x over previous
//
#include <hip/hip_runtime.h>
#include <math.h>
#include <stdint.h>

#define M_NODES 8192
#define E_DIM   512
#define NTOPK   6
#define ATTN_SCALE 0.04419417382415922f  // 512^-0.5

typedef __attribute__((ext_vector_type(8))) short short8;
typedef __attribute__((ext_vector_type(4))) float f32x4;

__device__ __forceinline__ float lrelu(float v) { return v > 0.f ? v : 0.01f * v; }

__device__ __forceinline__ unsigned short f2bf(float f) {
  uint32_t u = __float_as_uint(f);
  uint32_t r = (u + 0x7FFFu + ((u >> 16) & 1u)) >> 16;
  return (unsigned short)r;
}
__device__ __forceinline__ float bf2f(unsigned short s) {
  return __uint_as_float(((uint32_t)s) << 16);
}

// async 16B/lane global->LDS (wave-uniform LDS base, lane i lands at base+16i)
__device__ __forceinline__ void async_cp16(const void* gptr, void* lds) {
  auto g1 = reinterpret_cast<const __attribute__((address_space(1))) unsigned int*>(
      reinterpret_cast<uintptr_t>(gptr));
  auto l3 = reinterpret_cast<__attribute__((address_space(3))) unsigned int*>(
      reinterpret_cast<uintptr_t>(lds));
  __builtin_amdgcn_global_load_lds(g1, l3, 16, 0, 0);
}

// tiled bf16 layout: value (m,k), Ktiles=K/32:
//   idx = ((m>>4)*Ktiles + (k>>5))*512 + ((m&15) + 16*((k>>3)&3))*8 + (k&7)

// top-k key scheme (r6/r8-verified): key = ordered16(bf16) << 16 | (8191-col).
// ordered16: sign=0 -> h|0x8000 ; sign=1 -> ~h. Value order preserved, ties
// break to LOWER col (lax.top_k semantics). Keys unique per row.

// BK=64 K-loops (r12-verified): stage TWO 32-k tiles per barrier pair, slot
// (s*2+h)*512 <- source k-tile 2*kt8+h. Halves barrier/drain windows.

// ---------------------------------------------------------------------------
// Cast fp32 x + 6 weight matrices into bf16 frag-tiled layout.
// ---------------------------------------------------------------------------
__global__ __launch_bounds__(256) void wcast_kernel(
    const float* __restrict__ x, const float* __restrict__ fc1w,
    const float* __restrict__ whw, const float* __restrict__ wtw,
    const float* __restrict__ l1w, const float* __restrict__ l2w,
    const float* __restrict__ a1w,
    unsigned short* __restrict__ xT, unsigned short* __restrict__ fc1T,
    unsigned short* __restrict__ whT, unsigned short* __restrict__ wtT,
    unsigned short* __restrict__ l1T, unsigned short* __restrict__ l2T,
    unsigned short* __restrict__ a1T)
{
  const int gid = blockIdx.x * 256 + threadIdx.x;  // 0 .. 565247
  const float* src; unsigned short* dst; int K8, local;
  if (gid < 417792) {
    K8 = 48;
    if (gid < 393216) { src = x; dst = xT; local = gid; }
    else { src = fc1w; dst = fc1T; local = gid - 393216; }
  } else {
    K8 = 64;
    if (gid < 450560)      { src = whw; dst = whT; local = gid - 417792; }
    else if (gid < 483328) { src = wtw; dst = wtT; local = gid - 450560; }
    else if (gid < 516096) { src = l1w; dst = l1T; local = gid - 483328; }
    else if (gid < 548864) { src = l2w; dst = l2T; local = gid - 516096; }
    else                   { src = a1w; dst = a1T; local = gid - 548864; }
  }
  const int m = local / K8;
  const int k8 = local - m * K8;
  const float* p = src + (size_t)m * (K8 * 8) + k8 * 8;
  float4 v0 = ((const float4*)p)[0];
  float4 v1 = ((const float4*)p)[1];
  const int Kt = K8 >> 2;
  const size_t ti = ((size_t)(m >> 4) * Kt + (k8 >> 2)) * 512 + ((m & 15) + 16 * (k8 & 3)) * 8;
  uint4 pk;
  pk.x = (uint32_t)f2bf(v0.x) | ((uint32_t)f2bf(v0.y) << 16);
  pk.y = (uint32_t)f2bf(v0.z) | ((uint32_t)f2bf(v0.w) << 16);
  pk.z = (uint32_t)f2bf(v1.x) | ((uint32_t)f2bf(v1.y) << 16);
  pk.w = (uint32_t)f2bf(v1.z) | ((uint32_t)f2bf(v1.w) << 16);
  *(uint4*)(dst + ti) = pk;
}

// ---------------------------------------------------------------------------
// gemm1: hT = bf16(0.5*lrelu(x @ fc1^T + b)) tiled + fused column sums.
// 128x128 tile, grid (4,64), K=384: 6 BK=64 iterations.
// ---------------------------------------------------------------------------
__global__ __launch_bounds__(256, 4) void gemm1_kernel(
    const unsigned short* __restrict__ xT, const unsigned short* __restrict__ fc1T,
    const float* __restrict__ b1, unsigned short* __restrict__ hT,
    float* __restrict__ colsum)
{
  __shared__ unsigned short As[16 * 512];
  __shared__ unsigned short Bs[16 * 512];
  const int tid = threadIdx.x, lane = tid & 63, w = tid >> 6;
  const int wr = w >> 1, wc = w & 1;
  const int m0 = blockIdx.y * 128;
  const int n0 = blockIdx.x * 128;

  f32x4 acc[4][4];
#pragma unroll
  for (int i = 0; i < 4; i++)
#pragma unroll
    for (int j = 0; j < 4; j++) acc[i][j] = (f32x4){0.f, 0.f, 0.f, 0.f};

  auto stage = [&](int kt8) {
    const int s0 = w, s1 = w + 4;
#pragma unroll
    for (int h = 0; h < 2; h++) {
      const int kt = 2 * kt8 + h;
      async_cp16(xT + ((size_t)((m0 >> 4) + s0) * 12 + kt) * 512 + lane * 8, &As[(s0 * 2 + h) * 512]);
      async_cp16(xT + ((size_t)((m0 >> 4) + s1) * 12 + kt) * 512 + lane * 8, &As[(s1 * 2 + h) * 512]);
      async_cp16(fc1T + ((size_t)((n0 >> 4) + s0) * 12 + kt) * 512 + lane * 8, &Bs[(s0 * 2 + h) * 512]);
      async_cp16(fc1T + ((size_t)((n0 >> 4) + s1) * 12 + kt) * 512 + lane * 8, &Bs[(s1 * 2 + h) * 512]);
    }
  };
  stage(0);

  for (int kt8 = 0; kt8 < 6; kt8++) {
    __syncthreads();
#pragma unroll
    for (int h = 0; h < 2; h++) {
      short8 a[4], b[4];
#pragma unroll
      for (int i = 0; i < 4; i++) a[i] = *(const short8*)&As[((wr * 4 + i) * 2 + h) * 512 + lane * 8];
#pragma unroll
      for (int j = 0; j < 4; j++) b[j] = *(const short8*)&Bs[((wc * 4 + j) * 2 + h) * 512 + lane * 8];
#pragma unroll
      for (int i = 0; i < 4; i++)
#pragma unroll
        for (int j = 0; j < 4; j++)
          acc[i][j] = __builtin_amdgcn_mfma_f32_16x16x32_bf16(a[i], b[j], acc[i][j], 0, 0, 0);
    }
    __syncthreads();
    if (kt8 < 5) stage(kt8 + 1);
  }

  const int q = lane >> 4, lcol = lane & 15;
  float colp[4] = {};
#pragma unroll
  for (int i = 0; i < 4; i++)
#pragma unroll
    for (int j = 0; j < 4; j++) {
      const int c = n0 + wc * 64 + j * 16 + lcol;
      const float bias = b1[c];
#pragma unroll
      for (int d = 0; d < 4; d++) {
        const int r = m0 + wr * 64 + i * 16 + q * 4 + d;
        const float v = 0.5f * lrelu(acc[i][j][d] + bias);
        hT[((size_t)(r >> 4) * 16 + (c >> 5)) * 512 +
           ((r & 15) + 16 * ((c >> 3) & 3)) * 8 + (c & 7)] = f2bf(v);
        colp[j] += v;
      }
    }
#pragma unroll
  for (int j = 0; j < 4; j++) {
    colp[j] += __shfl_xor(colp[j], 16);
    colp[j] += __shfl_xor(colp[j], 32);
  }
  if (lane < 16) {
#pragma unroll
    for (int j = 0; j < 4; j++)
      atomicAdd(&colsum[n0 + wc * 64 + j * 16 + lcol], colp[j]);
  }
}

// ---------------------------------------------------------------------------
// meanproj: biasHT[c1024] = {wh_b|wt_b}[c] + (colsum/M) . {wh_w|wt_w}[c,:]
// (colsum holds 0.5-scaled sums, so this is Wh·(0.5·mean).) One wave per c.
// ---------------------------------------------------------------------------
__global__ __launch_bounds__(256) void meanproj_kernel(
    const float* __restrict__ colsum, const float* __restrict__ whw,
    const float* __restrict__ wtw, const float* __restrict__ whb,
    const float* __restrict__ wtb, float* __restrict__ biasHT)
{
  const int lane = threadIdx.x & 63;
  const int c1024 = blockIdx.x * 4 + (threadIdx.x >> 6);
  const bool isH = c1024 < 512;
  const int c = isH ? c1024 : c1024 - 512;
  const float* W = (isH ? whw : wtw) + (size_t)c * 512 + lane * 8;
  const float* cs = colsum + lane * 8;
  float s = 0.f;
#pragma unroll
  for (int e = 0; e < 8; e++) s = fmaf(cs[e], W[e], s);
#pragma unroll
  for (int off = 32; off; off >>= 1) s += __shfl_xor(s, off);
  if (lane == 0)
    biasHT[c1024] = (isH ? whb : wtb)[c] + s * (1.f / (float)M_NODES);
}

// ---------------------------------------------------------------------------
// dual_gemm: [e_h | e_t] = hT @ [Wh|Wt]^T + biasHT  (stacked 1024-col weight,
// whT/wtT contiguous). 128x128 tile, grid (8,64), K=512: 8 BK=64 iterations.
// Outputs: tiled (for sgemm) + ROW-MAJOR (for combine — r9 lesson).
// ---------------------------------------------------------------------------
__global__ __launch_bounds__(256, 4) void dual_gemm(
    const unsigned short* __restrict__ hT, const unsigned short* __restrict__ wstackT,
    const float* __restrict__ biasHT,
    unsigned short* __restrict__ ehT, unsigned short* __restrict__ etT,
    unsigned short* __restrict__ ehRow, unsigned short* __restrict__ etRow)
{
  __shared__ unsigned short As[16 * 512];
  __shared__ unsigned short Bs[16 * 512];
  const int tid = threadIdx.x, lane = tid & 63, w = tid >> 6;
  const int wr = w >> 1, wc = w & 1;
  const int m0 = blockIdx.y * 128;
  const int n0 = blockIdx.x * 128;  // [0,1024)

  f32x4 acc[4][4];
#pragma unroll
  for (int i = 0; i < 4; i++)
#pragma unroll
    for (int j = 0; j < 4; j++) acc[i][j] = (f32x4){0.f, 0.f, 0.f, 0.f};

  auto stage = [&](int kt8) {
    const int s0 = w, s1 = w + 4;
#pragma unroll
    for (int h = 0; h < 2; h++) {
      const int kt = 2 * kt8 + h;
      async_cp16(hT + ((size_t)((m0 >> 4) + s0) * 16 + kt) * 512 + lane * 8, &As[(s0 * 2 + h) * 512]);
      async_cp16(hT + ((size_t)((m0 >> 4) + s1) * 16 + kt) * 512 + lane * 8, &As[(s1 * 2 + h) * 512]);
      async_cp16(wstackT + ((size_t)((n0 >> 4) + s0) * 16 + kt) * 512 + lane * 8, &Bs[(s0 * 2 + h) * 512]);
      async_cp16(wstackT + ((size_t)((n0 >> 4) + s1) * 16 + kt) * 512 + lane * 8, &Bs[(s1 * 2 + h) * 512]);
    }
  };
  stage(0);

  for (int kt8 = 0; kt8 < 8; kt8++) {
    __syncthreads();
#pragma unroll
    for (int h = 0; h < 2; h++) {
      short8 a[4], b[4];
#pragma unroll
      for (int i = 0; i < 4; i++) a[i] = *(const short8*)&As[((wr * 4 + i) * 2 + h) * 512 + lane * 8];
#pragma unroll
      for (int j = 0; j < 4; j++) b[j] = *(const short8*)&Bs[((wc * 4 + j) * 2 + h) * 512 + lane * 8];
#pragma unroll
      for (int i = 0; i < 4; i++)
#pragma unroll
        for (int j = 0; j < 4; j++)
          acc[i][j] = __builtin_amdgcn_mfma_f32_16x16x32_bf16(a[i], b[j], acc[i][j], 0, 0, 0);
    }
    __syncthreads();
    if (kt8 < 7) stage(kt8 + 1);
  }

  const int q = lane >> 4, lcol = lane & 15;
  const bool isH = (n0 < 512);                 // block-uniform
  const int cb = isH ? n0 : (n0 - 512);
  unsigned short* T = isH ? ehT : etT;
  unsigned short* R = isH ? ehRow : etRow;

#pragma unroll
  for (int i = 0; i < 4; i++)
#pragma unroll
    for (int j = 0; j < 4; j++) {
      const int cl = wc * 64 + j * 16 + lcol;
      const float bias = biasHT[n0 + cl];
      const int c = cb + cl;
#pragma unroll
      for (int d = 0; d < 4; d++) {
        const int r = m0 + wr * 64 + i * 16 + q * 4 + d;
        const unsigned short us = f2bf(acc[i][j][d] + bias);
        T[((size_t)(r >> 4) * 16 + (c >> 5)) * 512 +
          ((r & 15) + 16 * ((c >> 3) & 3)) * 8 + (c & 7)] = us;
        R[(size_t)r * E_DIM + c] = us;
      }
    }
}

// ---------------------------------------------------------------------------
// MFMA GEMM, tile 128(M) x 64(N), 4 waves each 32x64, K-step 32.
// MODE 2: e = lrelu(A1@W1^T+b1)+lrelu(A2@W2^T+b2); T1 = bf16(e) tiled;
//         Cbf = bf16(e) row-major
// MODE 3: g[r] += sum_c lrelu(A@W1^T+b1)[r,c] * b2[c]  (fused gate readout)
// ---------------------------------------------------------------------------
template <int MODE>
__global__ __launch_bounds__(256) void mfma_gemm(
    const unsigned short* __restrict__ At1, const unsigned short* __restrict__ At2,
    const unsigned short* __restrict__ Wt1, const unsigned short* __restrict__ Wt2,
    const float* __restrict__ b1, const float* __restrict__ b2,
    float* __restrict__ Cf, unsigned short* __restrict__ T1,
    unsigned short* __restrict__ Cbf, int N, int K)
{
  constexpr bool DUALW = (MODE == 2);
  __shared__ unsigned short As[2][8 * 512];
  __shared__ unsigned short Bs[2][4 * 512];
  const int Kt = K >> 5;
  const int tid = threadIdx.x, lane = tid & 63, w = tid >> 6;
  const int m0 = blockIdx.y * 128, n0 = blockIdx.x * 64;

  f32x4 acc0[2][4], acc1[2][4];
#pragma unroll
  for (int p = 0; p < 2; p++)
#pragma unroll
    for (int j = 0; j < 4; j++) {
      acc0[p][j] = (f32x4){0.f, 0.f, 0.f, 0.f};
      acc1[p][j] = (f32x4){0.f, 0.f, 0.f, 0.f};
    }

  for (int kt = 0; kt < Kt; kt++) {
    const unsigned short* a1p = At1 + ((size_t)((m0 >> 4) + 2 * w) * Kt + kt) * 512 + lane * 8;
    async_cp16(a1p, &As[0][(2 * w) * 512]);
    async_cp16(a1p + (size_t)Kt * 512, &As[0][(2 * w + 1) * 512]);
    if (MODE == 2) {
      const unsigned short* a2p = At2 + ((size_t)((m0 >> 4) + 2 * w) * Kt + kt) * 512 + lane * 8;
      async_cp16(a2p, &As[1][(2 * w) * 512]);
      async_cp16(a2p + (size_t)Kt * 512, &As[1][(2 * w + 1) * 512]);
    }
    const unsigned short* bp1 = Wt1 + ((size_t)((n0 >> 4) + w) * Kt + kt) * 512 + lane * 8;
    async_cp16(bp1, &Bs[0][w * 512]);
    if (DUALW) {
      const unsigned short* bp2 = Wt2 + ((size_t)((n0 >> 4) + w) * Kt + kt) * 512 + lane * 8;
      async_cp16(bp2, &Bs[1][w * 512]);
    }
    __syncthreads();
    short8 a[2], a2[2], bb[4], bb2[4];
#pragma unroll
    for (int p = 0; p < 2; p++) a[p] = *(const short8*)&As[0][(2 * w + p) * 512 + lane * 8];
    if (MODE == 2) {
#pragma unroll
      for (int p = 0; p < 2; p++) a2[p] = *(const short8*)&As[1][(2 * w + p) * 512 + lane * 8];
    }
#pragma unroll
    for (int j = 0; j < 4; j++) bb[j] = *(const short8*)&Bs[0][j * 512 + lane * 8];
    if (DUALW) {
#pragma unroll
      for (int j = 0; j < 4; j++) bb2[j] = *(const short8*)&Bs[1][j * 512 + lane * 8];
    }
#pragma unroll
    for (int p = 0; p < 2; p++)
#pragma unroll
      for (int j = 0; j < 4; j++) {
        acc0[p][j] = __builtin_amdgcn_mfma_f32_16x16x32_bf16(a[p], bb[j], acc0[p][j], 0, 0, 0);
        if (MODE == 2)
          acc1[p][j] = __builtin_amdgcn_mfma_f32_16x16x32_bf16(a2[p], bb2[j], acc1[p][j], 0, 0, 0);
      }
    __syncthreads();
  }

  const int lrow = (lane >> 4) * 4, lcol = lane & 15;

  if (MODE == 3) {
    float part[2][4] = {};
#pragma unroll
    for (int p = 0; p < 2; p++)
#pragma unroll
      for (int j = 0; j < 4; j++) {
        const int c = n0 + j * 16 + lcol;
        const float bias1 = b1[c];
        const float w2 = b2[c];
#pragma unroll
        for (int d = 0; d < 4; d++)
          part[p][d] = fmaf(lrelu(acc0[p][j][d] + bias1), w2, part[p][d]);
      }
#pragma unroll
    for (int p = 0; p < 2; p++)
#pragma unroll
      for (int d = 0; d < 4; d++) {
#pragma unroll
        for (int off = 1; off < 16; off <<= 1)
          part[p][d] += __shfl_xor(part[p][d], off);
      }
    if (lcol == 0) {
#pragma unroll
      for (int p = 0; p < 2; p++)
#pragma unroll
        for (int d = 0; d < 4; d++)
          atomicAdd(&Cf[m0 + w * 32 + p * 16 + lrow + d], part[p][d]);
    }
    return;
  }

  const int NT = N >> 5;
#pragma unroll
  for (int p = 0; p < 2; p++)
#pragma unroll
    for (int j = 0; j < 4; j++) {
      const int c = n0 + j * 16 + lcol;
      const float bias1 = b1[c];
      const float bias2 = b2[c];
#pragma unroll
      for (int d = 0; d < 4; d++) {
        const int r = m0 + w * 32 + p * 16 + lrow + d;
        const float e = lrelu(acc0[p][j][d] + bias1) + lrelu(acc1[p][j][d] + bias2);
        T1[((size_t)(r >> 4) * NT + (c >> 5)) * 512 +
           ((r & 15) + 16 * ((c >> 3) & 3)) * 8 + (c & 7)] = f2bf(e);
        Cbf[(size_t)r * N + c] = f2bf(e);
      }
    }
}

// ---------------------------------------------------------------------------
// Score GEMM with fused per-128-col-block top-6. K-loop: 8 BK=64 iterations
// (staging 32KB aliased inside the 33,280B score tile; barrier count halved).
// Epilogue (r9-verified): permuted u32 dump + packed sign-transform +
// value-only prefilter + insertion sort + pair-merge + coalesced cand write.
// ---------------------------------------------------------------------------
__global__ __launch_bounds__(256, 4) void sgemm_kernel(
    const unsigned short* __restrict__ ehT, const unsigned short* __restrict__ etT,
    uint32_t* __restrict__ cand)
{
  __shared__ unsigned short SH[128 * 130];          // 33,280 B
  unsigned short* As = SH;                          // [0, 8192) u16  (16 KB)
  unsigned short* Bs = SH + 8192;                   // [8192, 16384) u16
  const int tid = threadIdx.x, lane = tid & 63, w = tid >> 6;
  const int wr = w >> 1, wc = w & 1;
  const int m0 = blockIdx.y * 128;
  const int n0 = blockIdx.x * 128;

  f32x4 acc[4][4];
#pragma unroll
  for (int i = 0; i < 4; i++)
#pragma unroll
    for (int j = 0; j < 4; j++) acc[i][j] = (f32x4){0.f, 0.f, 0.f, 0.f};

  auto stage = [&](int kt8) {
    const int s0 = w, s1 = w + 4;
#pragma unroll
    for (int h = 0; h < 2; h++) {
      const int kt = 2 * kt8 + h;
      async_cp16(ehT + ((size_t)((m0 >> 4) + s0) * 16 + kt) * 512 + lane * 8, &As[(s0 * 2 + h) * 512]);
      async_cp16(ehT + ((size_t)((m0 >> 4) + s1) * 16 + kt) * 512 + lane * 8, &As[(s1 * 2 + h) * 512]);
      async_cp16(etT + ((size_t)((n0 >> 4) + s0) * 16 + kt) * 512 + lane * 8, &Bs[(s0 * 2 + h) * 512]);
      async_cp16(etT + ((size_t)((n0 >> 4) + s1) * 16 + kt) * 512 + lane * 8, &Bs[(s1 * 2 + h) * 512]);
    }
  };
  stage(0);

  for (int kt8 = 0; kt8 < 8; kt8++) {
    __syncthreads();
#pragma unroll
    for (int h = 0; h < 2; h++) {
      short8 a[4], b[4];
#pragma unroll
      for (int i = 0; i < 4; i++) a[i] = *(const short8*)&As[((wr * 4 + i) * 2 + h) * 512 + lane * 8];
#pragma unroll
      for (int j = 0; j < 4; j++) b[j] = *(const short8*)&Bs[((wc * 4 + j) * 2 + h) * 512 + lane * 8];
#pragma unroll
      for (int i = 0; i < 4; i++)
#pragma unroll
        for (int j = 0; j < 4; j++)
          acc[i][j] = __builtin_amdgcn_mfma_f32_16x16x32_bf16(a[i], b[j], acc[i][j], 0, 0, 0);
    }
    __syncthreads();
    if (kt8 < 7) stage(kt8 + 1);
  }
  // Loop ended with a barrier; all staging reads retired -> SH reusable.

  const int q = lane >> 4, lcol = lane & 15;

  // dump bf16-rounded scores, permuted: SH[rowb][c'], c' = wc*64 + lcol*4 + j
#pragma unroll
  for (int i = 0; i < 4; i++)
#pragma unroll
    for (int d = 0; d < 4; d++) {
      const int rowb = wr * 64 + i * 16 + q * 4 + d;
      const uint32_t p01 = (uint32_t)f2bf(acc[i][0][d]) | ((uint32_t)f2bf(acc[i][1][d]) << 16);
      const uint32_t p23 = (uint32_t)f2bf(acc[i][2][d]) | ((uint32_t)f2bf(acc[i][3][d]) << 16);
      uint32_t* wp = (uint32_t*)(SH + rowb * 130 + wc * 64 + lcol * 4);
      wp[0] = p01;
      wp[1] = p23;
    }
  __syncthreads();

  // per-half-row scan: thread t -> row t>>1, half t&1 (c' in [half*64, +64))
  const int r = tid >> 1, half = tid & 1;
  const uint32_t* rowp = (const uint32_t*)SH + r * 65 + half * 32;
  uint32_t t0 = 0, t1 = 0, t2 = 0, t3 = 0, t4 = 0, t5 = 0;
#pragma unroll 8
  for (int cc = 0; cc < 32; cc++) {
    const uint32_t v = rowp[cc];
    const uint32_t sgn = v & 0x80008000u;
    const uint32_t ov = v ^ (0x80008000u | ((sgn >> 15) * 0x7FFFu));  // both ordered16
#pragma unroll
    for (int e = 0; e < 2; e++) {
      const uint32_t o16 = e ? (ov >> 16) : (ov & 0xFFFFu);
      if (o16 >= (t5 >> 16)) {            // value-only prefilter (exact reject)
        const int cperm = half * 64 + cc * 2 + e;
        const int col = n0 + (cperm >> 6) * 64 + (cperm & 3) * 16 + ((cperm >> 2) & 15);
        const uint32_t k = (o16 << 16) | (uint32_t)(8191 - col);
        if (k > t5) {
          t5 = k;
          uint32_t tmp;
          if (t5 > t4) { tmp = t4; t4 = t5; t5 = tmp; }
          if (t4 > t3) { tmp = t3; t3 = t4; t4 = tmp; }
          if (t3 > t2) { tmp = t2; t2 = t3; t3 = tmp; }
          if (t2 > t1) { tmp = t1; t1 = t2; t2 = tmp; }
          if (t1 > t0) { tmp = t0; t0 = t1; t1 = tmp; }
        }
      }
    }
  }

  // pair-merge (halves of the same row live in adjacent lanes)
  uint32_t b0 = (uint32_t)__shfl_xor((int)t0, 1);
  uint32_t b1 = (uint32_t)__shfl_xor((int)t1, 1);
  uint32_t b2 = (uint32_t)__shfl_xor((int)t2, 1);
  uint32_t b3 = (uint32_t)__shfl_xor((int)t3, 1);
  uint32_t b4 = (uint32_t)__shfl_xor((int)t4, 1);
  uint32_t b5 = (uint32_t)__shfl_xor((int)t5, 1);
  uint32_t wk[6];
#pragma unroll
  for (int t = 0; t < 6; t++) {
    if (t0 > b0) {
      wk[t] = t0;
      t0 = t1; t1 = t2; t2 = t3; t3 = t4; t4 = t5; t5 = 0u;
    } else {
      wk[t] = b0;
      b0 = b1; b1 = b2; b2 = b3; b3 = b4; b4 = b5; b5 = 0u;
    }
  }

  if (half == 0) {
    uint32_t* cp = cand + ((size_t)blockIdx.x * M_NODES + m0 + r) * 6;
    uint2 p01; p01.x = wk[0]; p01.y = wk[1];
    uint2 p23; p23.x = wk[2]; p23.y = wk[3];
    uint2 p45; p45.x = wk[4]; p45.y = wk[5];
    ((uint2*)cp)[0] = p01;
    ((uint2*)cp)[1] = p23;
    ((uint2*)cp)[2] = p45;
  }
}

// ---------------------------------------------------------------------------
// combine: exact global top-6 per row via 64-lane tournament merge of the
// 64 per-block sorted top-6 lists (lane l holds block l's list; head
// advanced by register shift). Row-major e_h/e_t reads (coalesced 1KB/row).
// Then the original combine math (softmax, gate, ka-softmax, s1/s2).
// ---------------------------------------------------------------------------
__global__ __launch_bounds__(256) void combine_kernel(
    const uint32_t* __restrict__ cand,
    const unsigned short* __restrict__ ehRow, const unsigned short* __restrict__ etRow,
    unsigned short* __restrict__ s1T, unsigned short* __restrict__ s2T)
{
  const int tid = threadIdx.x;
  const int lane = tid & 63;
  const int w = tid >> 6;
  const int row = blockIdx.x * 4 + w;
  const int m = row;

  const uint32_t* cp = cand + ((size_t)lane * M_NODES + row) * 6;
  const uint2 v01 = ((const uint2*)cp)[0];
  const uint2 v23 = ((const uint2*)cp)[1];
  const uint2 v45 = ((const uint2*)cp)[2];
  uint32_t a0 = v01.x, a1 = v01.y, a2 = v23.x, a3 = v23.y, a4 = v45.x, a5 = v45.y;

  float wv[NTOPK]; int id[NTOPK];
#pragma unroll
  for (int t = 0; t < NTOPK; t++) {
    uint32_t mm = a0;
#pragma unroll
    for (int off = 1; off < 64; off <<= 1) {
      const uint32_t o = (uint32_t)__shfl_xor((int)mm, off);
      mm = mm > o ? mm : o;
    }
    if (a0 == mm) {                    // unique keys -> exactly one winner
      a0 = a1; a1 = a2; a2 = a3; a3 = a4; a4 = a5; a5 = 0u;
    }
    // decode key -> (bf16 value as f32, col)
    const uint32_t h = mm >> 16;
    const uint32_t u = (h & 0x8000u) ? ((h & 0x7FFFu) << 16)
                                     : ((~h & 0xFFFFu) << 16);
    wv[t] = __uint_as_float(u) * ATTN_SCALE;
    id[t] = 8191 - (int)(mm & 0x1FFFu);
  }

  float mx = wv[0];
#pragma unroll
  for (int k = 1; k < NTOPK; k++) mx = fmaxf(mx, wv[k]);
  float p[NTOPK]; float s = 0.f;
#pragma unroll
  for (int k = 0; k < NTOPK; k++) { p[k] = expf(wv[k] - mx); s += p[k]; }
  const float inv = 1.f / s;
#pragma unroll
  for (int k = 0; k < NTOPK; k++) p[k] *= inv;

  short8 eh8 = *(const short8*)(ehRow + (size_t)m * E_DIM + lane * 8);
  float ehv[8];
#pragma unroll
  for (int e = 0; e < 8; e++) ehv[e] = bf2f((unsigned short)eh8[e]);

  float nv[NTOPK][8];
#pragma unroll
  for (int k = 0; k < NTOPK; k++) {
    short8 nb = *(const short8*)(etRow + (size_t)id[k] * E_DIM + lane * 8);
#pragma unroll
    for (int e = 0; e < 8; e++) nv[k][e] = bf2f((unsigned short)nb[e]);
  }

  float ka[NTOPK];
#pragma unroll
  for (int k = 0; k < NTOPK; k++) {
    float snb = 0.f, sg = 0.f;
    const float aa = 2.f - p[k], bb = p[k];
#pragma unroll
    for (int e = 0; e < 8; e++) {
      snb += nv[k][e];
      sg += tanhf(fmaf(aa, ehv[e], bb * nv[k][e]));
    }
#pragma unroll
    for (int off = 32; off; off >>= 1) {
      snb += __shfl_xor(snb, off);
      sg += __shfl_xor(sg, off);
    }
    ka[k] = snb * sg;
  }
  float km = ka[0];
#pragma unroll
  for (int k = 1; k < NTOPK; k++) km = fmaxf(km, ka[k]);
  float kp[NTOPK]; float ks = 0.f;
#pragma unroll
  for (int k = 0; k < NTOPK; k++) { kp[k] = expf(ka[k] - km); ks += kp[k]; }
  const float kinv = 1.f / ks;

  const size_t tbase = ((size_t)(m >> 4) * 16 + (lane >> 2)) * 512 +
                       ((m & 15) + 16 * (lane & 3)) * 8;
  unsigned short o1[8], o2[8];
#pragma unroll
  for (int e = 0; e < 8; e++) {
    float o = 0.f;
#pragma unroll
    for (int k = 0; k < NTOPK; k++) o = fmaf(kp[k], nv[k][e], o);
    o *= kinv;
    o1[e] = f2bf(ehv[e] + o);
    o2[e] = f2bf(ehv[e] * o);
  }
  *(short8*)(s1T + tbase) = *(short8*)o1;
  *(short8*)(s2T + tbase) = *(short8*)o2;
}

// ---------------------------------------------------------------------------
// pooled: unshifted exp(g) weights (|g| small, fp32-safe) + wsum atomic.
// ---------------------------------------------------------------------------
__global__ __launch_bounds__(256) void pooled_kernel(
    const unsigned short* __restrict__ emb, const float* __restrict__ g,
    float* __restrict__ pooled, float* __restrict__ wsum)
{
  const int t = threadIdx.x;
  const int r0 = blockIdx.x * 128;
  float a0 = 0.f, a1 = 0.f, lsum = 0.f;
  for (int r = 0; r < 128; r++) {
    const int m = r0 + r;
    const float wv = expf(g[m]);
    lsum += wv;
    a0 = fmaf(wv, bf2f(emb[(size_t)m * E_DIM + t]), a0);
    a1 = fmaf(wv, bf2f(emb[(size_t)m * E_DIM + 256 + t]), a1);
  }
  atomicAdd(&pooled[t], a0);
  atomicAdd(&pooled[t + 256], a1);
  if (t == 0) atomicAdd(wsum, lsum);
}

__global__ __launch_bounds__(512) void ln_kernel(
    const float* __restrict__ pooled, const float* __restrict__ wsum,
    const float* __restrict__ lng, const float* __restrict__ lnb,
    float* __restrict__ out)
{
  __shared__ float red[8];
  __shared__ float red2[8];
  const int t = threadIdx.x;
  const float v = pooled[t] / wsum[0];
  float s = v;
#pragma unroll
  for (int off = 32; off; off >>= 1) s += __shfl_xor(s, off);
  if ((t & 63) == 0) red[t >> 6] = s;
  __syncthreads();
  float tot = 0.f;
  for (int i = 0; i < 8; i++) tot += red[i];
  const float mu = tot / (float)E_DIM;
  const float d = v - mu;
  float q = d * d;
#pragma unroll
  for (int off = 32; off; off >>= 1) q += __shfl_xor(q, off);
  if ((t & 63) == 0) red2[t >> 6] = q;
  __syncthreads();
  float vt = 0.f;
  for (int i = 0; i < 8; i++) vt += red2[i];
  const float var = vt / (float)E_DIM;
  out[t] = d * rsqrtf(var + 1e-5f) * lng[t] + lnb[t];
}

// ---------------------------------------------------------------------------
extern "C" void kernel_launch(void* const* d_in, const int* in_sizes, int n_in,
                              void* d_out, int out_size, void* d_ws, size_t ws_size,
                              hipStream_t stream)
{
  const float* x     = (const float*)d_in[0];
  const float* fc1_w = (const float*)d_in[1];
  const float* fc1_b = (const float*)d_in[2];
  const float* wh_w  = (const float*)d_in[3];
  const float* wh_b  = (const float*)d_in[4];
  const float* wt_w  = (const float*)d_in[5];
  const float* wt_b  = (const float*)d_in[6];
  const float* l1_w  = (const float*)d_in[7];
  const float* l1_b  = (const float*)d_in[8];
  const float* l2_w  = (const float*)d_in[9];
  const float* l2_b  = (const float*)d_in[10];
  const float* a1_w  = (const float*)d_in[11];
  const float* a1_b  = (const float*)d_in[12];
  const float* a2_w  = (const float*)d_in[13];
  const float* a2_b  = (const float*)d_in[14];
  const float* ln_g  = (const float*)d_in[15];
  const float* ln_b  = (const float*)d_in[16];
  (void)a2_b;  // exactly cancels in softmax (shift invariance)

  char* ws = (char*)d_ws;
  const size_t MiB = 1 << 20;
  // weight tiles [0, 3M) — live whole run. NOTE: whT/wtT and l1T/l2T are each
  // contiguous pairs -> valid stacked 1024-row tiled tensors.
  unsigned short* fc1T = (unsigned short*)(ws + 0);
  unsigned short* whT  = (unsigned short*)(ws + 393216);
  unsigned short* wtT  = (unsigned short*)(ws + 917504);
  unsigned short* l1T  = (unsigned short*)(ws + 1441792);
  unsigned short* l2T  = (unsigned short*)(ws + 1966080);
  unsigned short* a1T  = (unsigned short*)(ws + 2490368);
  // activations:
  unsigned short* xT     = (unsigned short*)(ws + 3 * MiB);    // [3,9) wcast->gemm1
  unsigned short* hT     = (unsigned short*)(ws + 25 * MiB);   // [25,33) gemm1->dual_gemm
  unsigned short* ehT    = (unsigned short*)(ws + 33 * MiB);   // [33,41) dual_gemm->sgemm
  unsigned short* etT    = (unsigned short*)(ws + 41 * MiB);   // [41,49) dual_gemm->sgemm
  unsigned short* ehRow  = (unsigned short*)(ws + 49 * MiB);   // [49,57) dual_gemm->combine
  unsigned short* etRow  = (unsigned short*)(ws + 57 * MiB);   // [57,65) dual_gemm->combine
  unsigned short* s1T    = (unsigned short*)(ws + 3 * MiB);    // [3,11) combine->gemm3
  unsigned short* s2T    = (unsigned short*)(ws + 11 * MiB);   // [11,19) combine->gemm3
  unsigned short* embT   = (unsigned short*)(ws + 19 * MiB);   // [19,27) gemm3->gemm4
  unsigned short* embRow = (unsigned short*)(ws + 27 * MiB);   // [27,35) gemm3->pooled
  uint32_t*       cand   = (uint32_t*)(ws + 96 * MiB);         // [96,109) sgemm->combine (12.6MB)
  char*           smal   = ws + 69 * MiB;
  float* colsum = (float*)(smal);            // [0, 2048)
  float* biasHT = (float*)(smal + 2048);     // [2048, 6144)
  float* g      = (float*)(smal + 8192);     // [8192, 40960)
  float* stats  = (float*)(smal + 40960);    // wsum
  float* pooled = (float*)(smal + 45056);    // [45056, 47104)

  // zero colsum/g/wsum/pooled accumulators (biasHT fully overwritten)
  hipMemsetAsync(smal, 0, 47104, stream);

  // 0. cast x + all weights to bf16 tiled
  wcast_kernel<<<2208, 256, 0, stream>>>(x, fc1_w, wh_w, wt_w, l1_w, l2_w, a1_w,
                                         xT, fc1T, whT, wtT, l1T, l2T, a1T);
  // 1. hT = bf16(0.5*lrelu(x@fc1^T+b)) tiled + fused column sums (BK=64)
  gemm1_kernel<<<dim3(4, 64), 256, 0, stream>>>(xT, fc1T, fc1_b, hT, colsum);
  // 2. rank-1 mean projection folded into e_h/e_t biases
  meanproj_kernel<<<256, 256, 0, stream>>>(colsum, wh_w, wt_w, wh_b, wt_b, biasHT);
  // 3. [e_h|e_t] = hT @ [Wh|Wt]^T + biasHT -> tiled + row-major (BK=64)
  dual_gemm<<<dim3(8, 64), 256, 0, stream>>>(hT, whT, biasHT, ehT, etT, ehRow, etRow);
  // 4. score GEMM with fused LDS top-6 (BK=64 K-loop, packed-filter scan)
  sgemm_kernel<<<dim3(64, 64), 256, 0, stream>>>(ehT, etT, cand);
  // 5. exact global top-6 merge + combine (row-major e_h/e_t) -> s1T, s2T
  combine_kernel<<<M_NODES / 4, 256, 0, stream>>>(cand, ehRow, etRow, s1T, s2T);
  // 6. emb = lrelu(s1@l1^T+b1)+lrelu(s2@l2^T+b2) -> bf16 tiled + bf16 row
  mfma_gemm<2><<<dim3(8, 64), 256, 0, stream>>>(
      s1T, s2T, l1T, l2T, l1_b, l2_b, nullptr, embT, embRow, 512, 512);
  // 7. fused: g[m] = sum_c lrelu(emb@a1^T+b)[m,c] * a2w[c]
  mfma_gemm<3><<<dim3(4, 64), 256, 0, stream>>>(
      embT, nullptr, a1T, nullptr, a1_b, a2_w, g, nullptr, nullptr, 256, 512);
  // 8-9. pooled (fused softmax weights, 64 blk) + layernorm
  pooled_kernel<<<64, 256, 0, stream>>>(embRow, g, pooled, stats);
  ln_kernel<<<1, 512, 0, stream>>>(pooled, stats, ln_g, ln_b, (float*)d_out);
}